// Round 1
// baseline (1487.445 us; speedup 1.0000x reference)
//
#include <hip/hip_runtime.h>
#include <hip/hip_bf16.h>
#include <cstdint>
#include <cstddef>

// out[16384,64] = adj[16384,16384] @ (x[16384,64] @ W[64,64]) + bias[64]
// Strategy: support=x@W is tiny (134 MFLOP) -> prologue kernel writing
// TRANSPOSED bf16 supT[64][16384] into d_ws (2 MB, L2-resident).
// Main GEMM: bf16 MFMA 16x16x32, adj converted fp32->bf16 in-register.
// Memory-bound: adj = 1.073 GB read once -> ~170 us floor @ 6.3 TB/s.

#define NROWS 16384
#define NF 64
#define KSPLIT 4

typedef __attribute__((ext_vector_type(8))) short short8;
typedef __attribute__((ext_vector_type(4))) float f32x4;

__device__ __forceinline__ unsigned short f2bf(float f) {
  union { float f; unsigned u; } v; v.f = f;
  unsigned r = v.u + 0x7fffu + ((v.u >> 16) & 1u);  // RNE
  return (unsigned short)(r >> 16);
}

// out[idx] = bias[col]  (out re-poisoned 0xAA before every call; atomics need init)
__global__ void init_out_kernel(float* __restrict__ out, const float* __restrict__ bias) {
  int idx = blockIdx.x * 256 + threadIdx.x;
  out[idx] = bias[idx & (NF - 1)];
}

// supT[n][k] = sum_i x[k][i] * W[i][n], stored bf16, row stride NROWS.
// Block: 64 k-rows, 256 threads; thread t: n = t>>2, 16 consecutive k's.
__global__ __launch_bounds__(256) void support_kernel(
    const float* __restrict__ x, const float* __restrict__ w,
    unsigned short* __restrict__ supT) {
  __shared__ float sW[64 * 64];   // sW[i*64+n]: bank = n -> conflict-free broadcast
  __shared__ float sX[64 * 65];   // +1 pad breaks 4-way kb conflict
  const int t = threadIdx.x;
  const int k0 = blockIdx.x * 64;
  for (int i = t; i < 4096; i += 256) {
    sW[i] = w[i];
    sX[(i >> 6) * 65 + (i & 63)] = x[(size_t)k0 * 64 + i];
  }
  __syncthreads();
  const int n = t >> 2;
  const int kb = (t & 3) * 16;
  float acc[16];
#pragma unroll
  for (int kk = 0; kk < 16; ++kk) acc[kk] = 0.f;
  for (int i = 0; i < 64; ++i) {
    float wv = sW[i * 64 + n];
#pragma unroll
    for (int kk = 0; kk < 16; ++kk)
      acc[kk] += sX[(kb + kk) * 65 + i] * wv;
  }
  union { unsigned short us[16]; int4 v[2]; } u;
#pragma unroll
  for (int kk = 0; kk < 16; ++kk) u.us[kk] = f2bf(acc[kk]);
  int4* dst = reinterpret_cast<int4*>(supT + (size_t)n * NROWS + k0 + kb);  // 32B-aligned
  dst[0] = u.v[0];
  dst[1] = u.v[1];
}

// Main: out += adj @ supT^T. Wave = 16 rows x 64 cols (4 MFMA accs).
// Block = 4 waves = 64 rows; grid = (256 m-tiles, 4 k-splits) -> 16 waves/CU.
// No LDS, no barriers in the K-loop: A from HBM (fp32->bf16 cvt), B from L2.
__global__ __launch_bounds__(256, 4) void gcn_main_kernel(
    const float* __restrict__ adj, const unsigned short* __restrict__ supT,
    float* __restrict__ out) {
  const int lane = threadIdx.x & 63;
  const int wave = threadIdx.x >> 6;
  const int ln = lane & 15;      // A: m-index / B: n-index / D: col
  const int quad = lane >> 4;    // A,B: k-offset = quad*8 / D: row-base = quad*4
  const int m0 = blockIdx.x * 64 + wave * 16;
  const int kstart = blockIdx.y * (NROWS / KSPLIT);

  const float* ap = adj + (size_t)(m0 + ln) * NROWS + kstart + quad * 8;
  const short* sp = reinterpret_cast<const short*>(supT);
  const short* bp0 = sp + (size_t)(ln + 0)  * NROWS + kstart + quad * 8;
  const short* bp1 = sp + (size_t)(ln + 16) * NROWS + kstart + quad * 8;
  const short* bp2 = sp + (size_t)(ln + 32) * NROWS + kstart + quad * 8;
  const short* bp3 = sp + (size_t)(ln + 48) * NROWS + kstart + quad * 8;

  f32x4 acc0 = {0.f, 0.f, 0.f, 0.f};
  f32x4 acc1 = acc0, acc2 = acc0, acc3 = acc0;

#pragma unroll 2
  for (int kb = 0; kb < NROWS / KSPLIT; kb += 32) {
    float4 a0 = *reinterpret_cast<const float4*>(ap + kb);
    float4 a1 = *reinterpret_cast<const float4*>(ap + kb + 4);
    short8 b0 = *reinterpret_cast<const short8*>(bp0 + kb);
    short8 b1 = *reinterpret_cast<const short8*>(bp1 + kb);
    short8 b2 = *reinterpret_cast<const short8*>(bp2 + kb);
    short8 b3 = *reinterpret_cast<const short8*>(bp3 + kb);
    short8 af;
    af[0] = (short)f2bf(a0.x); af[1] = (short)f2bf(a0.y);
    af[2] = (short)f2bf(a0.z); af[3] = (short)f2bf(a0.w);
    af[4] = (short)f2bf(a1.x); af[5] = (short)f2bf(a1.y);
    af[6] = (short)f2bf(a1.z); af[7] = (short)f2bf(a1.w);
    acc0 = __builtin_amdgcn_mfma_f32_16x16x32_bf16(af, b0, acc0, 0, 0, 0);
    acc1 = __builtin_amdgcn_mfma_f32_16x16x32_bf16(af, b1, acc1, 0, 0, 0);
    acc2 = __builtin_amdgcn_mfma_f32_16x16x32_bf16(af, b2, acc2, 0, 0, 0);
    acc3 = __builtin_amdgcn_mfma_f32_16x16x32_bf16(af, b3, acc3, 0, 0, 0);
  }

  // D layout: col = lane&15, row = quad*4 + reg  [m89-verified]
  float* op = out + (size_t)(m0 + quad * 4) * NF + ln;
#pragma unroll
  for (int r = 0; r < 4; ++r) {
    atomicAdd(op + (size_t)r * NF + 0,  acc0[r]);
    atomicAdd(op + (size_t)r * NF + 16, acc1[r]);
    atomicAdd(op + (size_t)r * NF + 32, acc2[r]);
    atomicAdd(op + (size_t)r * NF + 48, acc3[r]);
  }
}

extern "C" void kernel_launch(void* const* d_in, const int* in_sizes, int n_in,
                              void* d_out, int out_size, void* d_ws, size_t ws_size,
                              hipStream_t stream) {
  const float* x    = (const float*)d_in[0];   // [16384,64]
  const float* adj  = (const float*)d_in[1];   // [16384,16384]
  const float* w    = (const float*)d_in[2];   // [64,64]
  const float* bias = (const float*)d_in[3];   // [64]
  float* out = (float*)d_out;                  // [16384,64]
  unsigned short* supT = (unsigned short*)d_ws; // needs 2 MB

  init_out_kernel<<<(NROWS * NF) / 256, 256, 0, stream>>>(out, bias);
  support_kernel<<<NROWS / 64, 256, 0, stream>>>(x, w, supT);
  gcn_main_kernel<<<dim3(NROWS / 64, KSPLIT), 256, 0, stream>>>(adj, supT, out);
}